// Round 11
// baseline (728.824 us; speedup 1.0000x reference)
//
#include <hip/hip_runtime.h>

#define D_IN  64
#define D_HID 16
#define D_OUT 32

#define CPB      64        // cols per bucket
#define CPB_SH   6
#define BAND_SH  15        // rows per band = 32768 (hs band = 2MB f32 <= XCD L2)
#define NBIN_MAX 6400      // max (band,bucket) bins: 4*1563=6252 for N=100K
#define BINB     64        // blocks in bincount/binfill (8/XCD: open-line set ~3.2MB < 4MB L2)

static __device__ __forceinline__ long long ntld_ll(const void* p) {
    return __builtin_nontemporal_load((const long long*)p);
}
static __device__ __forceinline__ int ntld_i(const int* p) {
    return __builtin_nontemporal_load(p);
}

// ---------------------------------------------------------------------------
// A: per-(block,bin) edge counts; bin = band(row)*NB + bucket(col).
//    LDS histogram, zero global atomics.
// ---------------------------------------------------------------------------
__global__ __launch_bounds__(256) void k_bincount(
        const int* __restrict__ ei, int* __restrict__ cntB,
        int E, int NB, int NBIN) {
    __shared__ int hist[NBIN_MAX];
    for (int b = threadIdx.x; b < NBIN; b += 256) hist[b] = 0;
    __syncthreads();
    int chunk = (E + BINB - 1) / BINB;
    int s = blockIdx.x * chunk;
    int e = min(E, s + chunk);
    for (int i = s + threadIdx.x; i < e; i += 256) {
        int r = ntld_i(ei + i);
        int c = ntld_i(ei + E + i);
        atomicAdd(&hist[(r >> BAND_SH) * NB + (c >> CPB_SH)], 1);
    }
    __syncthreads();
    for (int b = threadIdx.x; b < NBIN; b += 256)
        cntB[(size_t)b * BINB + blockIdx.x] = hist[b];
}

// ---------------------------------------------------------------------------
// B1: per-bin exclusive scan over BINB block counts; bin total -> bb[bin].
// ---------------------------------------------------------------------------
__global__ __launch_bounds__(BINB) void k_scanblk(int* __restrict__ cntB,
                                                  int* __restrict__ bb, int NBIN) {
    __shared__ int s[BINB];
    int b = blockIdx.x;
    int v = cntB[(size_t)b * BINB + threadIdx.x];
    s[threadIdx.x] = v;
    __syncthreads();
    for (int off = 1; off < BINB; off <<= 1) {
        int t = (threadIdx.x >= off) ? s[threadIdx.x - off] : 0;
        __syncthreads();
        s[threadIdx.x] += t;
        __syncthreads();
    }
    cntB[(size_t)b * BINB + threadIdx.x] = s[threadIdx.x] - v;  // exclusive
    if (threadIdx.x == BINB - 1) bb[b] = s[BINB - 1];           // total
}

// ---------------------------------------------------------------------------
// B2: exclusive scan of bin totals (tiled single block); bb[NBIN] = E.
// ---------------------------------------------------------------------------
__global__ void k_scanbase(int* __restrict__ bb, int NBIN) {
    __shared__ int s[512];
    __shared__ int basev;
    if (threadIdx.x == 0) basev = 0;
    __syncthreads();
    for (int start = 0; start < NBIN; start += 512) {
        int idx = start + threadIdx.x;
        int v = (idx < NBIN) ? bb[idx] : 0;
        s[threadIdx.x] = v;
        __syncthreads();
        for (int off = 1; off < 512; off <<= 1) {
            int t = (threadIdx.x >= off) ? s[threadIdx.x - off] : 0;
            __syncthreads();
            s[threadIdx.x] += t;
            __syncthreads();
        }
        if (idx < NBIN) bb[idx] = basev + s[threadIdx.x] - v;
        __syncthreads();
        if (threadIdx.x == 0) basev += s[511];
        __syncthreads();
    }
    if (threadIdx.x == 0) bb[NBIN] = basev;   // == E
}

// ---------------------------------------------------------------------------
// C: place edges into bin-contiguous runs reserved per (block,bin).
//    Pack (row | c_local<<20, w): row < 2^17 < 2^20, c_local in bits 20-25.
//    nt reads keep the streams from evicting the open write lines.
// ---------------------------------------------------------------------------
__global__ __launch_bounds__(256) void k_binfill(
        const int* __restrict__ ei, const float* __restrict__ w,
        const int* __restrict__ bb, const int* __restrict__ cntB,
        int2* __restrict__ binned, int E, int NB, int NBIN) {
    __shared__ int cur[NBIN_MAX];
    for (int b = threadIdx.x; b < NBIN; b += 256)
        cur[b] = bb[b] + cntB[(size_t)b * BINB + blockIdx.x];
    __syncthreads();
    int chunk = (E + BINB - 1) / BINB;
    int s = blockIdx.x * chunk;
    int e = min(E, s + chunk);
    for (int i = s + threadIdx.x; i < e; i += 256) {
        int r = ntld_i(ei + i);
        int c = ntld_i(ei + E + i);
        float wt = __builtin_nontemporal_load(w + i);
        int bin = (r >> BAND_SH) * NB + (c >> CPB_SH);
        int pos = atomicAdd(&cur[bin], 1);
        binned[pos] = make_int2(r | ((c & (CPB - 1)) << 20), __float_as_int(wt));
    }
}

// ---------------------------------------------------------------------------
// D: weighted in-degree per node: block = bucket, loops its nband segments.
//    dinv = rsqrt(1 + sum_w)  (self-loop weight 1 => always > 0).
// ---------------------------------------------------------------------------
__global__ __launch_bounds__(256) void k_deg(
        const int2* __restrict__ binned, const int* __restrict__ bb,
        float* __restrict__ dinv, int N, int NB, int nband) {
    __shared__ float wsum[CPB];
    if (threadIdx.x < CPB) wsum[threadIdx.x] = 0.f;
    __syncthreads();
    int b = blockIdx.x;
    for (int band = 0; band < nband; ++band) {
        int bs = bb[band * NB + b], be = bb[band * NB + b + 1];
        for (int i = bs + threadIdx.x; i < be; i += 256) {
            long long p = ntld_ll(binned + i);
            atomicAdd(&wsum[((int)p >> 20) & (CPB - 1)],
                      __int_as_float((int)(p >> 32)));
        }
    }
    __syncthreads();
    if (threadIdx.x < CPB) {
        int n = (b << CPB_SH) + threadIdx.x;
        if (n < N) dinv[n] = rsqrtf(1.0f + wsum[threadIdx.x]);
    }
}

// ---------------------------------------------------------------------------
// E: hs[n][f] = (x[n] . Wg[:,f]) * dinv[n].  16 nodes/block; x staged in LDS.
// ---------------------------------------------------------------------------
__global__ __launch_bounds__(256) void k_transform(
        const float4* __restrict__ x4,   // [N,16] float4 view of [N,64]
        const float* __restrict__ Wg,    // [64,16]
        const float* __restrict__ dinv,
        float* __restrict__ hs, int N) {
    __shared__ float Wl[D_IN * D_HID];
    __shared__ float xlf[16][68];
    for (int i = threadIdx.x; i < D_IN * D_HID; i += 256) Wl[i] = Wg[i];
    const int f = threadIdx.x & 15, nl = threadIdx.x >> 4;
    for (int base = blockIdx.x * 16; base < N; base += gridDim.x * 16) {
        __syncthreads();
        int n = base + nl;
        if (n < N) {
            float4 v = x4[(size_t)n * 16 + f];
            xlf[nl][f * 4 + 0] = v.x;
            xlf[nl][f * 4 + 1] = v.y;
            xlf[nl][f * 4 + 2] = v.z;
            xlf[nl][f * 4 + 3] = v.w;
        }
        __syncthreads();
        if (n < N) {
            float acc = 0.f;
#pragma unroll
            for (int k = 0; k < D_IN; ++k) acc += xlf[nl][k] * Wl[k * D_HID + f];
            hs[(size_t)n * D_HID + f] = acc * dinv[n];
        }
    }
}

// ---------------------------------------------------------------------------
// F: per-bucket aggregate, iterating row-bands in order (all blocks process
//    band k at ~the same time -> hot hs window = 1-2 bands = 2-4MB <= XCD L2).
//    binned stream is nt so it doesn't evict the band.
//    Epilogue: e = di*(acc + hs_self) + bg (hs_self already carries one di).
// ---------------------------------------------------------------------------
__global__ __launch_bounds__(256) void k_aggout(
        const int2* __restrict__ binned, const int* __restrict__ bb,
        const float* __restrict__ hs, const float* __restrict__ dinv,
        const float* __restrict__ bg, const float* __restrict__ Wo,
        const float* __restrict__ bo, float* __restrict__ out,
        int N, int NB, int nband) {
    __shared__ float acc[CPB][D_HID + 1];
    __shared__ float Wl[D_HID * D_OUT];
    __shared__ float bgl[D_HID];
    __shared__ float bol[D_OUT];
    for (int i = threadIdx.x; i < CPB * (D_HID + 1); i += 256)
        ((float*)acc)[i] = 0.f;
    for (int i = threadIdx.x; i < D_HID * D_OUT; i += 256) Wl[i] = Wo[i];
    if (threadIdx.x < D_HID) bgl[threadIdx.x] = bg[threadIdx.x];
    if (threadIdx.x < D_OUT) bol[threadIdx.x] = bo[threadIdx.x];
    __syncthreads();

    int b = blockIdx.x;
    const int f = threadIdx.x & 15;
    const int slot = threadIdx.x >> 4;          // 16 edge-slots
    for (int band = 0; band < nband; ++band) {
        int bs = bb[band * NB + b], be = bb[band * NB + b + 1];
        int i = bs + slot;
        for (; i + 16 < be; i += 32) {          // 2 independent gather chains
            long long p0 = ntld_ll(binned + i);
            long long p1 = ntld_ll(binned + i + 16);
            int r0 = (int)p0, r1 = (int)p1;
            float h0 = hs[(size_t)(r0 & 0xFFFFF) * D_HID + f];
            float h1 = hs[(size_t)(r1 & 0xFFFFF) * D_HID + f];
            atomicAdd(&acc[(r0 >> 20) & (CPB - 1)][f],
                      h0 * __int_as_float((int)(p0 >> 32)));
            atomicAdd(&acc[(r1 >> 20) & (CPB - 1)][f],
                      h1 * __int_as_float((int)(p1 >> 32)));
        }
        if (i < be) {
            long long p = ntld_ll(binned + i);
            int r = (int)p;
            float h = hs[(size_t)(r & 0xFFFFF) * D_HID + f];
            atomicAdd(&acc[(r >> 20) & (CPB - 1)][f],
                      h * __int_as_float((int)(p >> 32)));
        }
    }
    __syncthreads();

    {   // relu + bias + self-loop fold
        const int nl = threadIdx.x >> 4;
#pragma unroll
        for (int rep = 0; rep < CPB / 16; ++rep) {
            int cl = nl + rep * 16;
            int n = (b << CPB_SH) + cl;
            if (n < N) {
                float di = dinv[n];
                float v = di * (acc[cl][f] + hs[(size_t)n * D_HID + f]) + bgl[f];
                acc[cl][f] = fmaxf(v, 0.f);
            }
        }
    }
    __syncthreads();

    {   // out = emb @ Wo + bo
        const int o  = threadIdx.x & 31;
        const int n2 = threadIdx.x >> 5;
#pragma unroll
        for (int rep = 0; rep < CPB / 8; ++rep) {
            int cl = n2 + rep * 8;
            int n = (b << CPB_SH) + cl;
            if (n < N) {
                float a = bol[o];
#pragma unroll
                for (int ff = 0; ff < D_HID; ++ff)
                    a += acc[cl][ff] * Wl[ff * D_OUT + o];
                out[(size_t)n * D_OUT + o] = a;
            }
        }
    }
}

// ---------------------------------------------------------------------------
// Workspace (floats), ~32.4MB (< R8-proven 33.2MB budget):
//   dinv[N] | bb[NBIN+1 pad-even] | binned[2E] | hs[16N]
// cntB (NBIN*BINB ints = 1.6MB) overlays hs (dead after binfill;
// single-stream ordering makes the overlay safe). No memsets needed.
// ---------------------------------------------------------------------------
extern "C" void kernel_launch(void* const* d_in, const int* in_sizes, int n_in,
                              void* d_out, int out_size, void* d_ws, size_t ws_size,
                              hipStream_t stream) {
    const float* x  = (const float*)d_in[0];
    const int*   ei = (const int*)d_in[1];
    const float* ew = (const float*)d_in[2];
    const float* Wg = (const float*)d_in[3];
    const float* bg = (const float*)d_in[4];
    const float* Wo = (const float*)d_in[5];
    const float* bo = (const float*)d_in[6];
    float* out = (float*)d_out;

    const int N     = in_sizes[0] / D_IN;                    // 100000
    const int E     = in_sizes[2];                           // 3200000
    const int NB    = (N + CPB - 1) >> CPB_SH;               // 1563
    const int nband = (N + (1 << BAND_SH) - 1) >> BAND_SH;   // 4
    const int NBIN  = nband * NB;                            // 6252 <= NBIN_MAX

    float* ws     = (float*)d_ws;
    float* dinv   = ws;                                      // N
    int*   bb     = (int*)(ws + N);                          // NBIN+1
    size_t bbe    = (size_t)N + (size_t)((NBIN + 2) & ~1);   // even float offset
    int2*  binned = (int2*)(ws + bbe);                       // 2E floats, 8B-aligned
    float* hs     = ws + bbe + (size_t)2 * E;                // 16N
    int*   cntB   = (int*)hs;                                // NBIN*BINB overlay

    k_bincount<<<BINB, 256, 0, stream>>>(ei, cntB, E, NB, NBIN);
    k_scanblk <<<NBIN, BINB, 0, stream>>>(cntB, bb, NBIN);
    k_scanbase<<<1, 512, 0, stream>>>(bb, NBIN);
    k_binfill <<<BINB, 256, 0, stream>>>(ei, ew, bb, cntB, binned, E, NB, NBIN);
    k_deg     <<<NB, 256, 0, stream>>>(binned, bb, dinv, N, NB, nband);
    k_transform<<<(N + 15) / 16, 256, 0, stream>>>((const float4*)x, Wg, dinv, hs, N);
    k_aggout  <<<NB, 256, 0, stream>>>(binned, bb, hs, dinv, bg, Wo, bo, out,
                                       N, NB, nband);
}

// Round 12
// 593.965 us; speedup vs baseline: 1.2270x; 1.2270x over previous
//
#include <hip/hip_runtime.h>

#define D_IN  64
#define D_HID 16
#define D_OUT 32

#define CPB      64        // cols per bucket
#define CPB_SH   6
#define NB_MAX   1600      // max col-buckets (N <= 102400)
#define BINB     128       // blocks in bincount/binfill (R8-proven shape)
#define BAND2_SH 12        // rows per fine band = 4096 (hs window 256KB << XCD L2)
#define KB_MAX   32        // max fine bands (N <= 131072)
#define SEG_CAP  6144      // max staged bucket segment (48KB LDS)

static __device__ __forceinline__ long long ntld_ll(const void* p) {
    return __builtin_nontemporal_load((const long long*)p);
}
static __device__ __forceinline__ int ntld_i(const int* p) {
    return __builtin_nontemporal_load(p);
}

// ---------------------------------------------------------------------------
// A: per-(block,bucket) edge counts over col.  (R8-proven shape)
// ---------------------------------------------------------------------------
__global__ __launch_bounds__(256) void k_bincount(
        const int* __restrict__ col, int* __restrict__ cntB, int E, int NB) {
    __shared__ int hist[NB_MAX];
    for (int b = threadIdx.x; b < NB; b += 256) hist[b] = 0;
    __syncthreads();
    int chunk = (E + BINB - 1) / BINB;
    int s = blockIdx.x * chunk;
    int e = min(E, s + chunk);
    for (int i = s + threadIdx.x; i < e; i += 256)
        atomicAdd(&hist[ntld_i(col + i) >> CPB_SH], 1);
    __syncthreads();
    for (int b = threadIdx.x; b < NB; b += 256)
        cntB[(size_t)b * BINB + blockIdx.x] = hist[b];
}

// ---------------------------------------------------------------------------
// B1: per-bucket exclusive scan over BINB block counts; total -> bb[b].
// ---------------------------------------------------------------------------
__global__ __launch_bounds__(BINB) void k_scanblk(int* __restrict__ cntB,
                                                  int* __restrict__ bb, int NB) {
    __shared__ int s[BINB];
    int b = blockIdx.x;
    int v = cntB[(size_t)b * BINB + threadIdx.x];
    s[threadIdx.x] = v;
    __syncthreads();
    for (int off = 1; off < BINB; off <<= 1) {
        int t = (threadIdx.x >= off) ? s[threadIdx.x - off] : 0;
        __syncthreads();
        s[threadIdx.x] += t;
        __syncthreads();
    }
    cntB[(size_t)b * BINB + threadIdx.x] = s[threadIdx.x] - v;  // exclusive
    if (threadIdx.x == BINB - 1) bb[b] = s[BINB - 1];           // total
}

// ---------------------------------------------------------------------------
// B2: exclusive scan of bucket totals (tiled single block); bb[NB] = E.
// ---------------------------------------------------------------------------
__global__ void k_scanbase(int* __restrict__ bb, int NB) {
    __shared__ int s[512];
    __shared__ int basev;
    if (threadIdx.x == 0) basev = 0;
    __syncthreads();
    for (int start = 0; start < NB; start += 512) {
        int idx = start + threadIdx.x;
        int v = (idx < NB) ? bb[idx] : 0;
        s[threadIdx.x] = v;
        __syncthreads();
        for (int off = 1; off < 512; off <<= 1) {
            int t = (threadIdx.x >= off) ? s[threadIdx.x - off] : 0;
            __syncthreads();
            s[threadIdx.x] += t;
            __syncthreads();
        }
        if (idx < NB) bb[idx] = basev + s[threadIdx.x] - v;
        __syncthreads();
        if (threadIdx.x == 0) basev += s[511];
        __syncthreads();
    }
    if (threadIdx.x == 0) bb[NB] = basev;   // == E
}

// ---------------------------------------------------------------------------
// C: scatter edges into bucket-contiguous runs (R8-proven shape).
//    Pack (row | c_local<<20, w): row < 2^17, c_local bits 20-25.
// ---------------------------------------------------------------------------
__global__ __launch_bounds__(256) void k_binfill(
        const int* __restrict__ ei, const float* __restrict__ w,
        const int* __restrict__ bb, const int* __restrict__ cntB,
        int2* __restrict__ binned, int E, int NB) {
    __shared__ int cur[NB_MAX];
    for (int b = threadIdx.x; b < NB; b += 256)
        cur[b] = bb[b] + cntB[(size_t)b * BINB + blockIdx.x];
    __syncthreads();
    int chunk = (E + BINB - 1) / BINB;
    int s = blockIdx.x * chunk;
    int e = min(E, s + chunk);
    for (int i = s + threadIdx.x; i < e; i += 256) {
        int r = ntld_i(ei + i);
        int c = ntld_i(ei + E + i);
        float wt = __builtin_nontemporal_load(w + i);
        int pos = atomicAdd(&cur[c >> CPB_SH], 1);
        binned[pos] = make_int2(r | ((c & (CPB - 1)) << 20), __float_as_int(wt));
    }
}

// ---------------------------------------------------------------------------
// D (NEW): in-place per-bucket sort by fine row-band + dinv computation.
//    Block = bucket. Stage segment in LDS, count 25-band histogram + wsum,
//    scan (serial, 25 entries), scatter back band-sorted. Emits bb2 offsets.
//    len > SEG_CAP fallback: leave unsorted, one degenerate band (correct,
//    just slower for that bucket).
// ---------------------------------------------------------------------------
__global__ __launch_bounds__(256) void k_bandsort(
        int2* __restrict__ binned, const int* __restrict__ bb,
        int* __restrict__ bb2, float* __restrict__ dinv, int N, int kb) {
    __shared__ int2  seg[SEG_CAP];          // 48KB
    __shared__ float wsum[CPB];
    __shared__ int   cnt2[KB_MAX + 1];
    __shared__ int   cur2[KB_MAX];
    int b = blockIdx.x;
    int s = bb[b], e = bb[b + 1], len = e - s;
    if (threadIdx.x < CPB) wsum[threadIdx.x] = 0.f;
    if (threadIdx.x <= kb) cnt2[threadIdx.x] = 0;
    __syncthreads();

    if (len <= SEG_CAP) {                   // block-uniform branch
        for (int j = threadIdx.x; j < len; j += 256) {
            int2 v = binned[s + j];
            seg[j] = v;
            atomicAdd(&wsum[(v.x >> 20) & (CPB - 1)], __int_as_float(v.y));
            atomicAdd(&cnt2[(v.x & 0xFFFFF) >> BAND2_SH], 1);
        }
        __syncthreads();
        if (threadIdx.x == 0) {             // serial exclusive scan (kb=25)
            int run = s;
            for (int k = 0; k < kb; ++k) { int c = cnt2[k]; cnt2[k] = run; run += c; }
            cnt2[kb] = run;                 // == e
        }
        __syncthreads();
        if (threadIdx.x < kb)  cur2[threadIdx.x] = cnt2[threadIdx.x];
        if (threadIdx.x <= kb) bb2[(size_t)b * (kb + 1) + threadIdx.x] = cnt2[threadIdx.x];
        __syncthreads();
        for (int j = threadIdx.x; j < len; j += 256) {
            int2 v = seg[j];
            int pos = atomicAdd(&cur2[(v.x & 0xFFFFF) >> BAND2_SH], 1);
            binned[pos] = v;
        }
    } else {
        for (int j = threadIdx.x; j < len; j += 256) {
            int2 v = binned[s + j];
            atomicAdd(&wsum[(v.x >> 20) & (CPB - 1)], __int_as_float(v.y));
        }
        if (threadIdx.x <= kb)
            bb2[(size_t)b * (kb + 1) + threadIdx.x] = (threadIdx.x == 0) ? s : e;
    }
    __syncthreads();
    if (threadIdx.x < CPB) {
        int n = (b << CPB_SH) + threadIdx.x;
        if (n < N) dinv[n] = rsqrtf(1.0f + wsum[threadIdx.x]);
    }
}

// ---------------------------------------------------------------------------
// E: hs[n][f] = (x[n] . Wg[:,f]) * dinv[n].  16 nodes/block; x staged in LDS.
// ---------------------------------------------------------------------------
__global__ __launch_bounds__(256) void k_transform(
        const float4* __restrict__ x4, const float* __restrict__ Wg,
        const float* __restrict__ dinv, float* __restrict__ hs, int N) {
    __shared__ float Wl[D_IN * D_HID];
    __shared__ float xlf[16][68];
    for (int i = threadIdx.x; i < D_IN * D_HID; i += 256) Wl[i] = Wg[i];
    const int f = threadIdx.x & 15, nl = threadIdx.x >> 4;
    for (int base = blockIdx.x * 16; base < N; base += gridDim.x * 16) {
        __syncthreads();
        int n = base + nl;
        if (n < N) {
            float4 v = x4[(size_t)n * 16 + f];
            xlf[nl][f * 4 + 0] = v.x;
            xlf[nl][f * 4 + 1] = v.y;
            xlf[nl][f * 4 + 2] = v.z;
            xlf[nl][f * 4 + 3] = v.w;
        }
        __syncthreads();
        if (n < N) {
            float acc = 0.f;
#pragma unroll
            for (int k = 0; k < D_IN; ++k) acc += xlf[nl][k] * Wl[k * D_HID + f];
            hs[(size_t)n * D_HID + f] = acc * dinv[n];
        }
    }
}

// ---------------------------------------------------------------------------
// F: per-bucket aggregate walking FINE bands via bb2 (256KB hot hs window),
//    then fused relu + output GEMM. Epilogue: e = di*(acc + hs_self) + bg.
// ---------------------------------------------------------------------------
__global__ __launch_bounds__(256) void k_aggout(
        const int2* __restrict__ binned, const int* __restrict__ bb2,
        const float* __restrict__ hs, const float* __restrict__ dinv,
        const float* __restrict__ bg, const float* __restrict__ Wo,
        const float* __restrict__ bo, float* __restrict__ out, int N, int kb) {
    __shared__ float acc[CPB][D_HID + 1];
    __shared__ float Wl[D_HID * D_OUT];
    __shared__ float bgl[D_HID];
    __shared__ float bol[D_OUT];
    for (int i = threadIdx.x; i < CPB * (D_HID + 1); i += 256)
        ((float*)acc)[i] = 0.f;
    for (int i = threadIdx.x; i < D_HID * D_OUT; i += 256) Wl[i] = Wo[i];
    if (threadIdx.x < D_HID) bgl[threadIdx.x] = bg[threadIdx.x];
    if (threadIdx.x < D_OUT) bol[threadIdx.x] = bo[threadIdx.x];
    __syncthreads();

    int b = blockIdx.x;
    const int f = threadIdx.x & 15;
    const int slot = threadIdx.x >> 4;          // 16 edge-slots
    for (int k = 0; k < kb; ++k) {
        int bs = bb2[(size_t)b * (kb + 1) + k];
        int be = bb2[(size_t)b * (kb + 1) + k + 1];
        int i = bs + slot;
        for (; i + 16 < be; i += 32) {          // 2 independent gather chains
            long long p0 = ntld_ll(binned + i);
            long long p1 = ntld_ll(binned + i + 16);
            int r0 = (int)p0, r1 = (int)p1;
            float h0 = hs[(size_t)(r0 & 0xFFFFF) * D_HID + f];
            float h1 = hs[(size_t)(r1 & 0xFFFFF) * D_HID + f];
            atomicAdd(&acc[(r0 >> 20) & (CPB - 1)][f],
                      h0 * __int_as_float((int)(p0 >> 32)));
            atomicAdd(&acc[(r1 >> 20) & (CPB - 1)][f],
                      h1 * __int_as_float((int)(p1 >> 32)));
        }
        if (i < be) {
            long long p = ntld_ll(binned + i);
            int r = (int)p;
            float h = hs[(size_t)(r & 0xFFFFF) * D_HID + f];
            atomicAdd(&acc[(r >> 20) & (CPB - 1)][f],
                      h * __int_as_float((int)(p >> 32)));
        }
    }
    __syncthreads();

    {   // relu + bias + self-loop fold (hs_self already carries one di)
        const int nl = threadIdx.x >> 4;
#pragma unroll
        for (int rep = 0; rep < CPB / 16; ++rep) {
            int cl = nl + rep * 16;
            int n = (b << CPB_SH) + cl;
            if (n < N) {
                float di = dinv[n];
                float v = di * (acc[cl][f] + hs[(size_t)n * D_HID + f]) + bgl[f];
                acc[cl][f] = fmaxf(v, 0.f);
            }
        }
    }
    __syncthreads();

    {   // out = emb @ Wo + bo
        const int o  = threadIdx.x & 31;
        const int n2 = threadIdx.x >> 5;
#pragma unroll
        for (int rep = 0; rep < CPB / 8; ++rep) {
            int cl = n2 + rep * 8;
            int n = (b << CPB_SH) + cl;
            if (n < N) {
                float a = bol[o];
#pragma unroll
                for (int ff = 0; ff < D_HID; ++ff)
                    a += acc[cl][ff] * Wl[ff * D_OUT + o];
                out[(size_t)n * D_OUT + o] = a;
            }
        }
    }
}

// ---------------------------------------------------------------------------
// Workspace (floats), ~32.6MB (< R8-proven budget):
//   dinv[N] | bb[NB+1 pad] | bb2[NB*(kb+1) pad] | binned[2E] | hs[16N]
// cntB (NB*BINB = 800KB) overlays hs (dead after binfill; stream-ordered).
// ---------------------------------------------------------------------------
extern "C" void kernel_launch(void* const* d_in, const int* in_sizes, int n_in,
                              void* d_out, int out_size, void* d_ws, size_t ws_size,
                              hipStream_t stream) {
    const float* x  = (const float*)d_in[0];
    const int*   ei = (const int*)d_in[1];
    const float* ew = (const float*)d_in[2];
    const float* Wg = (const float*)d_in[3];
    const float* bg = (const float*)d_in[4];
    const float* Wo = (const float*)d_in[5];
    const float* bo = (const float*)d_in[6];
    float* out = (float*)d_out;

    const int N  = in_sizes[0] / D_IN;                      // 100000
    const int E  = in_sizes[2];                             // 3200000
    const int NB = (N + CPB - 1) >> CPB_SH;                 // 1563
    const int kb = (N + (1 << BAND2_SH) - 1) >> BAND2_SH;   // 25 (<= KB_MAX)

    float* ws   = (float*)d_ws;
    float* dinv = ws;                                            // N
    int*   bb   = (int*)(ws + N);                                // NB+1
    size_t o2   = (size_t)N + (size_t)((NB + 2) & ~1);
    int*   bb2  = (int*)(ws + o2);                               // NB*(kb+1)
    size_t o3   = o2 + (((size_t)NB * (kb + 1) + 1) & ~(size_t)1);
    int2*  binned = (int2*)(ws + o3);                            // 2E floats
    float* hs   = ws + o3 + (size_t)2 * E;                       // 16N
    int*   cntB = (int*)hs;                                      // NB*BINB overlay

    k_bincount<<<BINB, 256, 0, stream>>>(ei + E, cntB, E, NB);
    k_scanblk <<<NB, BINB, 0, stream>>>(cntB, bb, NB);
    k_scanbase<<<1, 512, 0, stream>>>(bb, NB);
    k_binfill <<<BINB, 256, 0, stream>>>(ei, ew, bb, cntB, binned, E, NB);
    k_bandsort<<<NB, 256, 0, stream>>>(binned, bb, bb2, dinv, N, kb);
    k_transform<<<(N + 15) / 16, 256, 0, stream>>>((const float4*)x, Wg, dinv, hs, N);
    k_aggout  <<<NB, 256, 0, stream>>>(binned, bb2, hs, dinv, bg, Wo, bo, out, N, kb);
}

// Round 13
// 588.880 us; speedup vs baseline: 1.2376x; 1.0086x over previous
//
#include <hip/hip_runtime.h>

#define D_IN  64
#define D_HID 16
#define D_OUT 32

#define CPB      32        // cols per bucket
#define CPB_SH   5
#define NB_MAX   3200      // max col-buckets (N <= 102400)
#define BINB     128       // blocks in bincount/binfill (R8/R12-proven shape)
#define BAND2_SH 12        // rows per fine band = 4096 (sort granularity)
#define KB_MAX   32        // max fine bands (N <= 131072)
#define SEG_CAP  2048      // max staged bucket segment (16KB LDS; avg len 1024)

static __device__ __forceinline__ long long ntld_ll(const void* p) {
    return __builtin_nontemporal_load((const long long*)p);
}
static __device__ __forceinline__ int ntld_i(const int* p) {
    return __builtin_nontemporal_load(p);
}

// ---------------------------------------------------------------------------
// A: per-(block,bucket) edge counts over col.
// ---------------------------------------------------------------------------
__global__ __launch_bounds__(256) void k_bincount(
        const int* __restrict__ col, int* __restrict__ cntB, int E, int NB) {
    __shared__ int hist[NB_MAX];
    for (int b = threadIdx.x; b < NB; b += 256) hist[b] = 0;
    __syncthreads();
    int chunk = (E + BINB - 1) / BINB;
    int s = blockIdx.x * chunk;
    int e = min(E, s + chunk);
    for (int i = s + threadIdx.x; i < e; i += 256)
        atomicAdd(&hist[ntld_i(col + i) >> CPB_SH], 1);
    __syncthreads();
    for (int b = threadIdx.x; b < NB; b += 256)
        cntB[(size_t)b * BINB + blockIdx.x] = hist[b];
}

// ---------------------------------------------------------------------------
// B1: per-bucket exclusive scan over BINB block counts; total -> bb[b].
// ---------------------------------------------------------------------------
__global__ __launch_bounds__(BINB) void k_scanblk(int* __restrict__ cntB,
                                                  int* __restrict__ bb, int NB) {
    __shared__ int s[BINB];
    int b = blockIdx.x;
    int v = cntB[(size_t)b * BINB + threadIdx.x];
    s[threadIdx.x] = v;
    __syncthreads();
    for (int off = 1; off < BINB; off <<= 1) {
        int t = (threadIdx.x >= off) ? s[threadIdx.x - off] : 0;
        __syncthreads();
        s[threadIdx.x] += t;
        __syncthreads();
    }
    cntB[(size_t)b * BINB + threadIdx.x] = s[threadIdx.x] - v;  // exclusive
    if (threadIdx.x == BINB - 1) bb[b] = s[BINB - 1];           // total
}

// ---------------------------------------------------------------------------
// B2: exclusive scan of bucket totals (tiled single block); bb[NB] = E.
// ---------------------------------------------------------------------------
__global__ void k_scanbase(int* __restrict__ bb, int NB) {
    __shared__ int s[512];
    __shared__ int basev;
    if (threadIdx.x == 0) basev = 0;
    __syncthreads();
    for (int start = 0; start < NB; start += 512) {
        int idx = start + threadIdx.x;
        int v = (idx < NB) ? bb[idx] : 0;
        s[threadIdx.x] = v;
        __syncthreads();
        for (int off = 1; off < 512; off <<= 1) {
            int t = (threadIdx.x >= off) ? s[threadIdx.x - off] : 0;
            __syncthreads();
            s[threadIdx.x] += t;
            __syncthreads();
        }
        if (idx < NB) bb[idx] = basev + s[threadIdx.x] - v;
        __syncthreads();
        if (threadIdx.x == 0) basev += s[511];
        __syncthreads();
    }
    if (threadIdx.x == 0) bb[NB] = basev;   // == E
}

// ---------------------------------------------------------------------------
// C: scatter edges into bucket-contiguous runs.
//    Pack (row | c_local<<20, w): row < 2^17, c_local bits 20-24.
// ---------------------------------------------------------------------------
__global__ __launch_bounds__(256) void k_binfill(
        const int* __restrict__ ei, const float* __restrict__ w,
        const int* __restrict__ bb, const int* __restrict__ cntB,
        int2* __restrict__ binned, int E, int NB) {
    __shared__ int cur[NB_MAX];
    for (int b = threadIdx.x; b < NB; b += 256)
        cur[b] = bb[b] + cntB[(size_t)b * BINB + blockIdx.x];
    __syncthreads();
    int chunk = (E + BINB - 1) / BINB;
    int s = blockIdx.x * chunk;
    int e = min(E, s + chunk);
    for (int i = s + threadIdx.x; i < e; i += 256) {
        int r = ntld_i(ei + i);
        int c = ntld_i(ei + E + i);
        float wt = __builtin_nontemporal_load(w + i);
        int pos = atomicAdd(&cur[c >> CPB_SH], 1);
        binned[pos] = make_int2(r | ((c & (CPB - 1)) << 20), __float_as_int(wt));
    }
}

// ---------------------------------------------------------------------------
// D: in-place per-bucket sort by fine row-band (locality for aggout's walk)
//    + dinv computation. len > SEG_CAP fallback: skip sort (correct, slower).
// ---------------------------------------------------------------------------
__global__ __launch_bounds__(256) void k_bandsort(
        int2* __restrict__ binned, const int* __restrict__ bb,
        float* __restrict__ dinv, int N, int kb) {
    __shared__ int2  seg[SEG_CAP];          // 16KB
    __shared__ float wsum[CPB];
    __shared__ int   cnt2[KB_MAX + 1];
    __shared__ int   cur2[KB_MAX];
    int b = blockIdx.x;
    int s = bb[b], e = bb[b + 1], len = e - s;
    if (threadIdx.x < CPB) wsum[threadIdx.x] = 0.f;
    if (threadIdx.x <= kb) cnt2[threadIdx.x] = 0;
    __syncthreads();

    if (len <= SEG_CAP) {                   // block-uniform branch
        for (int j = threadIdx.x; j < len; j += 256) {
            int2 v = binned[s + j];
            seg[j] = v;
            atomicAdd(&wsum[(v.x >> 20) & (CPB - 1)], __int_as_float(v.y));
            atomicAdd(&cnt2[(v.x & 0xFFFFF) >> BAND2_SH], 1);
        }
        __syncthreads();
        if (threadIdx.x == 0) {             // serial exclusive scan (kb~25)
            int run = s;
            for (int k = 0; k < kb; ++k) { int c = cnt2[k]; cnt2[k] = run; run += c; }
            cnt2[kb] = run;                 // == e
        }
        __syncthreads();
        if (threadIdx.x < kb) cur2[threadIdx.x] = cnt2[threadIdx.x];
        __syncthreads();
        for (int j = threadIdx.x; j < len; j += 256) {
            int2 v = seg[j];
            int pos = atomicAdd(&cur2[(v.x & 0xFFFFF) >> BAND2_SH], 1);
            binned[pos] = v;
        }
    } else {
        for (int j = threadIdx.x; j < len; j += 256) {
            int2 v = binned[s + j];
            atomicAdd(&wsum[(v.x >> 20) & (CPB - 1)], __int_as_float(v.y));
        }
    }
    __syncthreads();
    if (threadIdx.x < CPB) {
        int n = (b << CPB_SH) + threadIdx.x;
        if (n < N) dinv[n] = rsqrtf(1.0f + wsum[threadIdx.x]);
    }
}

// ---------------------------------------------------------------------------
// E: hs[n][f] = (x[n] . Wg[:,f]) * dinv[n].  16 nodes/block; x staged in LDS.
// ---------------------------------------------------------------------------
__global__ __launch_bounds__(256) void k_transform(
        const float4* __restrict__ x4, const float* __restrict__ Wg,
        const float* __restrict__ dinv, float* __restrict__ hs, int N) {
    __shared__ float Wl[D_IN * D_HID];
    __shared__ float xlf[16][68];
    for (int i = threadIdx.x; i < D_IN * D_HID; i += 256) Wl[i] = Wg[i];
    const int f = threadIdx.x & 15, nl = threadIdx.x >> 4;
    for (int base = blockIdx.x * 16; base < N; base += gridDim.x * 16) {
        __syncthreads();
        int n = base + nl;
        if (n < N) {
            float4 v = x4[(size_t)n * 16 + f];
            xlf[nl][f * 4 + 0] = v.x;
            xlf[nl][f * 4 + 1] = v.y;
            xlf[nl][f * 4 + 2] = v.z;
            xlf[nl][f * 4 + 3] = v.w;
        }
        __syncthreads();
        if (n < N) {
            float acc = 0.f;
#pragma unroll
            for (int k = 0; k < D_IN; ++k) acc += xlf[nl][k] * Wl[k * D_HID + f];
            hs[(size_t)n * D_HID + f] = acc * dinv[n];
        }
    }
}

// ---------------------------------------------------------------------------
// F: per-bucket aggregate — LINEAR walk of the band-sorted segment with
//    8 INDEPENDENT gather chains per thread (32 lines in flight per wave,
//    4x R12's MLP). Then fused relu + output GEMM.
// ---------------------------------------------------------------------------
__global__ __launch_bounds__(256) void k_aggout(
        const int2* __restrict__ binned, const int* __restrict__ bb,
        const float* __restrict__ hs, const float* __restrict__ dinv,
        const float* __restrict__ bg, const float* __restrict__ Wo,
        const float* __restrict__ bo, float* __restrict__ out, int N) {
    __shared__ float acc[CPB][D_HID + 1];
    __shared__ float Wl[D_HID * D_OUT];
    __shared__ float bgl[D_HID];
    __shared__ float bol[D_OUT];
    for (int i = threadIdx.x; i < CPB * (D_HID + 1); i += 256)
        ((float*)acc)[i] = 0.f;
    for (int i = threadIdx.x; i < D_HID * D_OUT; i += 256) Wl[i] = Wo[i];
    if (threadIdx.x < D_HID) bgl[threadIdx.x] = bg[threadIdx.x];
    if (threadIdx.x < D_OUT) bol[threadIdx.x] = bo[threadIdx.x];
    __syncthreads();

    int b = blockIdx.x;
    int bs = bb[b], be = bb[b + 1];
    const int f = threadIdx.x & 15;
    const int slot = threadIdx.x >> 4;          // 16 edge-slots
    int i = bs + slot;
    // main: 8 independent chains (edges i, i+16, ..., i+112), step 128
    for (; i + 112 < be; i += 128) {
        long long p[8];
#pragma unroll
        for (int j = 0; j < 8; ++j) p[j] = ntld_ll(binned + i + 16 * j);
        float h[8];
#pragma unroll
        for (int j = 0; j < 8; ++j)
            h[j] = hs[(size_t)((int)p[j] & 0xFFFFF) * D_HID + f];
#pragma unroll
        for (int j = 0; j < 8; ++j)
            atomicAdd(&acc[((int)p[j] >> 20) & (CPB - 1)][f],
                      h[j] * __int_as_float((int)(p[j] >> 32)));
    }
    // tail: single chain
    for (; i < be; i += 16) {
        long long p = ntld_ll(binned + i);
        int r = (int)p;
        float h = hs[(size_t)(r & 0xFFFFF) * D_HID + f];
        atomicAdd(&acc[(r >> 20) & (CPB - 1)][f],
                  h * __int_as_float((int)(p >> 32)));
    }
    __syncthreads();

    {   // relu + bias + self-loop fold (hs_self already carries one di)
        const int nl = threadIdx.x >> 4;
#pragma unroll
        for (int rep = 0; rep < CPB / 16; ++rep) {
            int cl = nl + rep * 16;
            int n = (b << CPB_SH) + cl;
            if (n < N) {
                float di = dinv[n];
                float v = di * (acc[cl][f] + hs[(size_t)n * D_HID + f]) + bgl[f];
                acc[cl][f] = fmaxf(v, 0.f);
            }
        }
    }
    __syncthreads();

    {   // out = emb @ Wo + bo
        const int o  = threadIdx.x & 31;
        const int n2 = threadIdx.x >> 5;
#pragma unroll
        for (int rep = 0; rep < CPB / 8; ++rep) {
            int cl = n2 + rep * 8;
            int n = (b << CPB_SH) + cl;
            if (n < N) {
                float a = bol[o];
#pragma unroll
                for (int ff = 0; ff < D_HID; ++ff)
                    a += acc[cl][ff] * Wl[ff * D_OUT + o];
                out[(size_t)n * D_OUT + o] = a;
            }
        }
    }
}

// ---------------------------------------------------------------------------
// Workspace (floats), ~32.4MB:
//   dinv[N] | bb[NB+1 pad] | binned[2E] | hs[16N]
// cntB (NB*BINB = 1.6MB) overlays hs (dead after binfill; stream-ordered).
// ---------------------------------------------------------------------------
extern "C" void kernel_launch(void* const* d_in, const int* in_sizes, int n_in,
                              void* d_out, int out_size, void* d_ws, size_t ws_size,
                              hipStream_t stream) {
    const float* x  = (const float*)d_in[0];
    const int*   ei = (const int*)d_in[1];
    const float* ew = (const float*)d_in[2];
    const float* Wg = (const float*)d_in[3];
    const float* bg = (const float*)d_in[4];
    const float* Wo = (const float*)d_in[5];
    const float* bo = (const float*)d_in[6];
    float* out = (float*)d_out;

    const int N  = in_sizes[0] / D_IN;                      // 100000
    const int E  = in_sizes[2];                             // 3200000
    const int NB = (N + CPB - 1) >> CPB_SH;                 // 3125
    const int kb = (N + (1 << BAND2_SH) - 1) >> BAND2_SH;   // 25 (<= KB_MAX)

    float* ws   = (float*)d_ws;
    float* dinv = ws;                                            // N
    int*   bb   = (int*)(ws + N);                                // NB+1
    size_t o2   = (size_t)N + (size_t)((NB + 2) & ~1);
    int2*  binned = (int2*)(ws + o2);                            // 2E floats
    float* hs   = ws + o2 + (size_t)2 * E;                       // 16N
    int*   cntB = (int*)hs;                                      // NB*BINB overlay

    k_bincount<<<BINB, 256, 0, stream>>>(ei + E, cntB, E, NB);
    k_scanblk <<<NB, BINB, 0, stream>>>(cntB, bb, NB);
    k_scanbase<<<1, 512, 0, stream>>>(bb, NB);
    k_binfill <<<BINB, 256, 0, stream>>>(ei, ew, bb, cntB, binned, E, NB);
    k_bandsort<<<NB, 256, 0, stream>>>(binned, bb, dinv, N, kb);
    k_transform<<<(N + 15) / 16, 256, 0, stream>>>((const float4*)x, Wg, dinv, hs, N);
    k_aggout  <<<NB, 256, 0, stream>>>(binned, bb, hs, dinv, bg, Wo, bo, out, N);
}